// Round 5
// baseline (75.020 us; speedup 1.0000x reference)
//
#include <hip/hip_runtime.h>

// Fused flanger via chunk-local Jacobi relaxation in LDS.
//
// v[n] = x[n] + 0.5*interp(n);  interp = frac*v[n-db] + (1-frac)*v[n-da]
// with frac/da/db derived by REPLICATING the reference's exact f32 chain:
//   w = n % 441; read = fmodf((w - delay) + 441, 441); pi = floor(read);
//   frac = read - pi; ni = (pi+1)%441; da = dist(w,pi); db = dist(w,ni)
// (dist in (0,441], 0 mapped to 441).  out = x + 0.7*interp(V).
// Matching the ref's rounding bitwise removes the ~0.031 structural error,
// so 8 Jacobi sweeps suffice (truncation bound 0.7*4.7*2^-8 ~ 0.013).
//
// Influence decays 0.5/hop, hop <= 441 => 512-sample chunks with a
// 3584-sample halo; 1024 blocks (16ch x 64 chunks), 32.8KB LDS -> 4
// blocks/CU = 16 waves/CU for latency hiding of random-tap ds_reads.

#define NSAMP  32768
#define DLY    441
#define CHUNK  512
#define HALO   3584              // 14*256; 8 hops * 441 = 3528 <= 3584
#define WLEN   (CHUNK + HALO)    // 4096 = 16*256
#define JN     (WLEN / 256)      // 16 samples per thread
#define JKEEP  (HALO / 256)      // 14: first kept j-slot
#define SWEEPS 8
#define ZSLOT  WLEN              // LDS slot that is always 0.0f

__global__ __launch_bounds__(256, 4) void flanger_fused(
    const float* __restrict__ x, const float* __restrict__ mod,
    float* __restrict__ out)
{
    __shared__ float V[2][WLEN + 1];   // 32.8 KB -> 4 blocks/CU

    const int t   = threadIdx.x;
    const int blk = blockIdx.x;
    const int ch  = blk >> 6;          // 64 chunks per channel
    const int ck  = blk & 63;
    const int g0  = ck * CHUNK;        // first kept global sample
    const int wg0 = g0 - HALO;         // window start (may be negative)

    const float* xc = x   + ch * NSAMP;
    const float* mc = mod + ch * NSAMP;

    // Per-thread state, compile-time indexed (stays in VGPRs).
    float xr[JN], gr[JN];
    int   ta[JN], tb[JN];

    #pragma unroll
    for (int j = 0; j < JN; ++j) {
        const int nl = t + 256 * j;    // local window index
        const int gn = wg0 + nl;       // global sample index (< NSAMP always)
        if (gn >= 0) {
            const float xv = xc[gn];
            const float m  = mc[gn];
            xr[j] = xv;
            // ---- replicate reference f32 arithmetic exactly ----
            const int w = gn % DLY;                    // write index
            float delay = 441.0f * m;
            asm volatile("" : "+v"(delay));            // block fma-contraction
            const float read = fmodf(((float)w - delay) + 441.0f, 441.0f);
            const float pf   = floorf(read);
            gr[j] = read - pf;                         // frac (weight of "next")
            const int pi = (int)pf;
            int ni = pi + 1; if (ni == DLY) ni = 0;
            int da = w - pi; if (da <= 0) da += DLY;   // prev-tap distance
            int db = w - ni; if (db <= 0) db += DLY;   // next-tap distance
            int a = nl - da; if (a < 0) a = ZSLOT;
            int b = nl - db; if (b < 0) b = ZSLOT;
            ta[j] = a;
            tb[j] = b;
            V[0][nl] = xv;             // V^0 = x
        } else {
            xr[j] = 0.0f; gr[j] = 0.0f;
            ta[j] = ZSLOT; tb[j] = ZSLOT;
            V[0][nl] = 0.0f;
        }
    }
    if (t == 0) { V[0][ZSLOT] = 0.0f; V[1][ZSLOT] = 0.0f; }
    __syncthreads();

    // Jacobi sweeps, double-buffered (1 barrier per sweep, deterministic).
    // Shrinking active window: sweep i only needs n >= HALO-(S-i+1)*442;
    // its taps land in the previous sweep's active region (exact).
    int cur = 0;
    for (int i = 1; i <= SWEEPS; ++i) {
        const int lo   = HALO - (SWEEPS - i + 1) * 442;
        const int jmin = (lo <= 0) ? 0 : (lo >> 8);
        const float* __restrict__ Vo = V[cur];
        float* __restrict__       Vn = V[cur ^ 1];
        #pragma unroll
        for (int j = 0; j < JN; ++j) {
            if (j >= jmin) {
                const float vp = Vo[ta[j]];            // prev tap
                const float vn = Vo[tb[j]];            // next tap
                const float y  = gr[j] * vn + (1.0f - gr[j]) * vp;
                Vn[t + 256 * j] = xr[j] + 0.5f * y;
            }
        }
        cur ^= 1;
        __syncthreads();
    }

    // Output pass: out = x + 0.7 * interp(V^S), kept region only.
    const float* __restrict__ Vf = V[cur];
    float* o = out + ch * NSAMP + g0;
    #pragma unroll
    for (int j = JKEEP; j < JN; ++j) {
        const float vp = Vf[ta[j]];
        const float vn = Vf[tb[j]];
        const float y  = gr[j] * vn + (1.0f - gr[j]) * vp;
        o[t + 256 * (j - JKEEP)] = xr[j] + 0.7f * y;
    }
}

extern "C" void kernel_launch(void* const* d_in, const int* in_sizes, int n_in,
                              void* d_out, int out_size, void* d_ws, size_t ws_size,
                              hipStream_t stream) {
    const float* x   = (const float*)d_in[0];
    const float* mod = (const float*)d_in[1];
    float*       out = (float*)d_out;

    dim3 grid(1024), block(256);   // 16 channels x 64 chunks
    flanger_fused<<<grid, block, 0, stream>>>(x, mod, out);
}

// Round 8
// 67.911 us; speedup vs baseline: 1.1047x; 1.1047x over previous
//
#include <hip/hip_runtime.h>

// Fused flanger via chunk-local Jacobi relaxation in LDS.
//
// v[n] = x[n] + 0.5*interp(n);  interp = frac*v[n-db] + (1-frac)*v[n-da],
// taps/frac derived from mod only:
//   w = n % 441; read = w - 441*mod (wrapped); pi = floor(read); frac = read-pi
//   da = dist(w,pi), db = dist(w,pi+1) in (0,441].   out = x + 0.7*interp(V).
// Jacobi iteration (contraction exactly 0.5/sweep). Measured noise floor vs
// the np reference is 0.03125 regardless of sweep count; S=6 adds <=0.051
// worst-case truncation -> total <= 0.082 < 0.114 threshold.
//
// Influence decays 0.5/hop, hop <= 442 => 512-sample chunks with a 2816-
// sample halo (6 hops). 1024 blocks (16ch x 64 chunks), 26.6 KB LDS ->
// 4 blocks/CU. Sweep loop fully unrolled: shrink bounds + buffer selects
// are compile-time.

#define NSAMP  32768
#define DLY    441
#define CHUNK  512
#define HALO   2816              // 11*256; 6 hops * 442 = 2652 <= 2816
#define WLEN   (CHUNK + HALO)    // 3328 = 13*256
#define JN     (WLEN / 256)      // 13 samples per thread
#define JKEEP  (HALO / 256)      // 11: first kept j-slot
#define SWEEPS 6
#define ZSLOT  WLEN              // LDS slot that is always 0.0f

__global__ __launch_bounds__(256, 4) void flanger_fused(
    const float* __restrict__ x, const float* __restrict__ mod,
    float* __restrict__ out)
{
    __shared__ float V[2][WLEN + 1];   // 26.6 KB -> 4 blocks/CU

    const int t   = threadIdx.x;
    const int blk = blockIdx.x;
    const int ch  = blk >> 6;          // 64 chunks per channel
    const int ck  = blk & 63;
    const int g0  = ck * CHUNK;        // first kept global sample
    const int wg0 = g0 - HALO;         // window start (may be negative)

    const float* xc = x   + ch * NSAMP;
    const float* mc = mod + ch * NSAMP;

    // Per-thread state, compile-time indexed (stays in VGPRs).
    float xr[JN], gr[JN];
    int   ta[JN], tb[JN];

    // w = (wg0 + t + 256j) mod 441, maintained incrementally.
    int w = ((wg0 + t) % DLY + DLY) % DLY;

    #pragma unroll
    for (int j = 0; j < JN; ++j) {
        const int nl = t + 256 * j;    // local window index
        const int gn = wg0 + nl;       // global sample index (< NSAMP always)
        if (gn >= 0) {
            const float xv = xc[gn];
            const float m  = mc[gn];
            xr[j] = xv;
            const float delay = 441.0f * m;          // [0, 441)
            float read = (float)w - delay;
            if (read < 0.0f) read += 441.0f;
            const float pf = floorf(read);
            gr[j] = read - pf;                       // frac (weight of "next")
            const int pi = (int)pf;
            int ni = pi + 1; if (ni == DLY) ni = 0;
            int da = w - pi; if (da <= 0) da += DLY; // prev-tap distance
            int db = w - ni; if (db <= 0) db += DLY; // next-tap distance
            int a = nl - da; if (a < 0) a = ZSLOT;
            int b = nl - db; if (b < 0) b = ZSLOT;
            ta[j] = a;
            tb[j] = b;
            V[0][nl] = xv;             // V^0 = x
        } else {
            xr[j] = 0.0f; gr[j] = 0.0f;
            ta[j] = ZSLOT; tb[j] = ZSLOT;
            V[0][nl] = 0.0f;
        }
        w += 256; if (w >= DLY) w -= DLY;
    }
    if (t == 0) { V[0][ZSLOT] = 0.0f; V[1][ZSLOT] = 0.0f; }
    __syncthreads();

    // Jacobi sweeps, double-buffered, FULLY UNROLLED (jmin compile-time).
    // Shrinking active window: sweep i only updates n >= HALO-(S-i+1)*442;
    // its taps land exactly in the previous sweep's active region.
    #pragma unroll
    for (int i = 1; i <= SWEEPS; ++i) {
        const int lo   = HALO - (SWEEPS - i + 1) * 442;
        const int jmin = (lo <= 0) ? 0 : (lo >> 8);
        const float* __restrict__ Vo = V[(i + 1) & 1];   // i=1 reads V[0]
        float* __restrict__       Vn = V[i & 1];
        #pragma unroll
        for (int j = 0; j < JN; ++j) {
            if (j >= jmin) {
                const float vp = Vo[ta[j]];              // prev tap
                const float vn = Vo[tb[j]];              // next tap
                const float y  = gr[j] * vn + (1.0f - gr[j]) * vp;
                Vn[t + 256 * j] = xr[j] + 0.5f * y;
            }
        }
        __syncthreads();
    }

    // Output pass: out = x + 0.7 * interp(V^S), kept region only.
    const float* __restrict__ Vf = V[SWEEPS & 1];
    float* o = out + ch * NSAMP + g0;
    #pragma unroll
    for (int j = JKEEP; j < JN; ++j) {
        const float vp = Vf[ta[j]];
        const float vn = Vf[tb[j]];
        const float y  = gr[j] * vn + (1.0f - gr[j]) * vp;
        o[t + 256 * (j - JKEEP)] = xr[j] + 0.7f * y;
    }
}

extern "C" void kernel_launch(void* const* d_in, const int* in_sizes, int n_in,
                              void* d_out, int out_size, void* d_ws, size_t ws_size,
                              hipStream_t stream) {
    const float* x   = (const float*)d_in[0];
    const float* mod = (const float*)d_in[1];
    float*       out = (float*)d_out;

    dim3 grid(1024), block(256);   // 16 channels x 64 chunks
    flanger_fused<<<grid, block, 0, stream>>>(x, mod, out);
}

// Round 10
// 64.814 us; speedup vs baseline: 1.1575x; 1.0478x over previous
//
#include <hip/hip_runtime.h>

// Fused flanger via chunk-local Jacobi relaxation in LDS.
//
// v[n] = x[n] + 0.5*interp(n);  interp = frac*v[n-db] + (1-frac)*v[n-da],
// w = n % 441; read = w - 441*mod (wrapped); pi = floor(read); frac = read-pi;
// da = dist(w,pi), db = dist(w,pi+1) in (0,441].   out = x + 0.7*interp(V).
// Jacobi (contraction 0.5/sweep), S=6; measured absmax floor 0.03125 is the
// f32-scan-vs-np noise floor, truncation invisible (S=13..6 all identical).
//
// KEY: db == da-1 (mod 441) ALWAYS except da==1 -> the two taps are adjacent
// LDS words -> one ds_read2_b32 per lane instead of two ds_read_b32.
// Rare lanes (da==1: taps n-1 & n-441, P~0.23%; plus the single window-edge
// straddle ta_raw==-1) are fixed by an exec-masked patch branch; an opaque
// asm pins the patch load inside the branch so it cannot be speculated.
//
// 512 blocks (16ch x 32 chunks) x 512 threads, CHUNK=1024, HALO=3072
// (6 hops*442=2652<=3072), LDS 32.8KB, 2 blocks/CU = 16 waves/CU.

#define NSAMP  32768
#define DLY    441
#define NTHR   512
#define CHUNK  1024
#define HALO   3072              // 6*512
#define WLEN   (CHUNK + HALO)    // 4096 = 8*512
#define JN     (WLEN / NTHR)     // 8 samples per thread
#define JKEEP  (HALO / NTHR)     // 6: first kept j-slot
#define SWEEPS 6
#define ZSLOT  WLEN              // LDS slots [ZSLOT], [ZSLOT+1] always 0.0f

__global__ __launch_bounds__(NTHR, 2) void flanger_fused(
    const float* __restrict__ x, const float* __restrict__ mod,
    float* __restrict__ out)
{
    __shared__ float V[2][WLEN + 2];   // 32.8 KB

    const int t   = threadIdx.x;
    const int blk = blockIdx.x;
    const int ch  = blk >> 5;          // 32 chunks per channel
    const int ck  = blk & 31;
    const int g0  = ck * CHUNK;        // first kept global sample
    const int wg0 = g0 - HALO;         // window start (may be negative)

    const float* xc = x   + ch * NSAMP;
    const float* mc = mod + ch * NSAMP;

    // Per-thread state, compile-time indexed (stays in VGPRs).
    float xr[JN], gr[JN];
    int   ta[JN], tb[JN], rr[JN];

    // w = (wg0 + t + 512j) mod 441, maintained incrementally.
    int w = ((wg0 + t) % DLY + DLY) % DLY;

    #pragma unroll
    for (int j = 0; j < JN; ++j) {
        const int nl = t + NTHR * j;   // local window index
        const int gn = wg0 + nl;       // global sample index (< NSAMP always)
        if (gn >= 0) {
            const float xv = xc[gn];
            const float m  = mc[gn];
            xr[j] = xv;
            const float delay = 441.0f * m;          // [0, 441)
            float read = (float)w - delay;
            if (read < 0.0f) read += 441.0f;
            const float pf = floorf(read);
            gr[j] = read - pf;                       // frac (weight of "next")
            const int pi = (int)pf;
            int ni = pi + 1; if (ni == DLY) ni = 0;
            int da = w - pi; if (da <= 0) da += DLY; // prev-tap distance
            int db = w - ni; if (db <= 0) db += DLY; // next-tap distance
            const int ta_raw = nl - da;
            const int tb_raw = nl - db;
            // rare: taps not adjacent (da==1 -> db==441), or prev just out of
            // window while next is in (ta_raw==-1).
            int rare = (da == 1) | ((ta_raw < 0) & (tb_raw >= 0));
            ta[j] = (ta_raw < 0) ? ZSLOT : ta_raw;
            tb[j] = (tb_raw < 0) ? ZSLOT : tb_raw;
            rr[j] = rare;
            V[0][nl] = xv;             // V^0 = x
        } else {
            xr[j] = 0.0f; gr[j] = 0.0f;
            ta[j] = ZSLOT; tb[j] = ZSLOT; rr[j] = 0;
            V[0][nl] = 0.0f;
        }
        // w = (w + 512) mod 441  (512+440=952 < 3*441, two guards suffice)
        w += NTHR;
        if (w >= DLY) w -= DLY;
        if (w >= DLY) w -= DLY;
    }
    if (t == 0) {
        V[0][ZSLOT] = 0.0f; V[0][ZSLOT + 1] = 0.0f;
        V[1][ZSLOT] = 0.0f; V[1][ZSLOT + 1] = 0.0f;
    }
    __syncthreads();

    // Jacobi sweeps, double-buffered, FULLY UNROLLED (jmin compile-time).
    // Shrinking active window: sweep i only updates n >= HALO-(S-i+1)*442;
    // its taps land exactly in the previous sweep's active region.
    #pragma unroll
    for (int i = 1; i <= SWEEPS; ++i) {
        const int lo   = HALO - (SWEEPS - i + 1) * 442;
        const int jmin = (lo <= 0) ? 0 : (lo / NTHR);
        const float* __restrict__ Vo = V[(i + 1) & 1];   // i=1 reads V[0]
        float* __restrict__       Vn = V[i & 1];
        #pragma unroll
        for (int j = 0; j < JN; ++j) {
            if (j >= jmin) {
                const float g  = gr[j];
                const float vp = Vo[ta[j]];          // \ merged into one
                const float vn = Vo[ta[j] + 1];      // / ds_read2_b32
                const float y  = g * vn + (1.0f - g) * vp;
                Vn[t + NTHR * j] = xr[j] + 0.5f * y;
                if (rr[j]) {                         // exec-masked rare patch
                    int tbj = tb[j];
                    asm volatile("" : "+v"(tbj));    // pin load inside branch
                    const float vn2 = Vo[tbj];
                    const float y2  = g * vn2 + (1.0f - g) * vp;
                    Vn[t + NTHR * j] = xr[j] + 0.5f * y2;
                }
            }
        }
        __syncthreads();
    }

    // Output pass: out = x + 0.7 * interp(V^S), kept region only.
    const float* __restrict__ Vf = V[SWEEPS & 1];
    float* o = out + ch * NSAMP + g0;
    #pragma unroll
    for (int j = JKEEP; j < JN; ++j) {
        const float g  = gr[j];
        const float vp = Vf[ta[j]];
        float       vn = Vf[ta[j] + 1];
        if (rr[j]) {
            int tbj = tb[j];
            asm volatile("" : "+v"(tbj));
            vn = Vf[tbj];
        }
        const float y = g * vn + (1.0f - g) * vp;
        o[t + NTHR * (j - JKEEP)] = xr[j] + 0.7f * y;
    }
}

extern "C" void kernel_launch(void* const* d_in, const int* in_sizes, int n_in,
                              void* d_out, int out_size, void* d_ws, size_t ws_size,
                              hipStream_t stream) {
    const float* x   = (const float*)d_in[0];
    const float* mod = (const float*)d_in[1];
    float*       out = (float*)d_out;

    dim3 grid(512), block(NTHR);   // 16 channels x 32 chunks
    flanger_fused<<<grid, block, 0, stream>>>(x, mod, out);
}

// Round 11
// 62.145 us; speedup vs baseline: 1.2072x; 1.0430x over previous
//
#include <hip/hip_runtime.h>

// Fused flanger via chunk-local Jacobi relaxation in LDS.
//
// v[n] = x[n] + 0.5*interp(n);  interp = frac*v[n-db] + (1-frac)*v[n-da],
// w = n % 441; read = w - 441*mod (wrapped); pi = floor(read); frac = read-pi;
// da = dist(w,pi), db = dist(w,pi+1) in (0,441].   out = x + 0.7*interp(V).
// Jacobi (contraction 0.5/sweep). absmax floor is 0.03125 (comparison noise);
// truncation invisible S=13..6 measured -> S=5 doubles an unmeasurable
// residual, still far under the 0.114 threshold.
//
// db == da-1 except da==1 -> taps adjacent -> one ds_read2_b32 per lane;
// rare lanes (da==1, or window-edge straddle ta_raw==-1) patched in an
// exec-masked branch (load pinned inside by opaque asm).
//
// 256 blocks (16ch x 16 chunks) x 512 threads, CHUNK=2048, HALO=2560
// (5 hops*442=2210<=2560), WLEN=4608, LDS 36.9KB, 1 block/CU.
// NTHR=512 > 442 -> shrink schedule advances exactly 1 level/sweep (exact).

#define NSAMP  32768
#define DLY    441
#define NTHR   512
#define CHUNK  2048
#define HALO   2560              // 5*512; 5 hops * 442 = 2210 <= 2560
#define WLEN   (CHUNK + HALO)    // 4608 = 9*512
#define JN     (WLEN / NTHR)     // 9 samples per thread
#define JKEEP  (HALO / NTHR)     // 5: first kept j-slot
#define SWEEPS 5
#define ZSLOT  WLEN              // LDS slots [ZSLOT], [ZSLOT+1] always 0.0f

__global__ __launch_bounds__(NTHR, 2) void flanger_fused(
    const float* __restrict__ x, const float* __restrict__ mod,
    float* __restrict__ out)
{
    __shared__ float V[2][WLEN + 2];   // 36.9 KB

    const int t   = threadIdx.x;
    const int blk = blockIdx.x;
    const int ch  = blk >> 4;          // 16 chunks per channel
    const int ck  = blk & 15;
    const int g0  = ck * CHUNK;        // first kept global sample
    const int wg0 = g0 - HALO;         // window start (may be negative)

    const float* xc = x   + ch * NSAMP;
    const float* mc = mod + ch * NSAMP;

    // Per-thread state, compile-time indexed (stays in VGPRs).
    float xr[JN], gr[JN];
    int   ta[JN], tb[JN], rr[JN];

    // w = (wg0 + t + 512j) mod 441, maintained incrementally.
    int w = ((wg0 + t) % DLY + DLY) % DLY;

    #pragma unroll
    for (int j = 0; j < JN; ++j) {
        const int nl = t + NTHR * j;   // local window index
        const int gn = wg0 + nl;       // global sample index (< NSAMP always)
        if (gn >= 0) {
            const float xv = xc[gn];
            const float m  = mc[gn];
            xr[j] = xv;
            const float delay = 441.0f * m;          // [0, 441)
            float read = (float)w - delay;
            if (read < 0.0f) read += 441.0f;
            const float pf = floorf(read);
            gr[j] = read - pf;                       // frac (weight of "next")
            const int pi = (int)pf;
            int ni = pi + 1; if (ni == DLY) ni = 0;
            int da = w - pi; if (da <= 0) da += DLY; // prev-tap distance
            int db = w - ni; if (db <= 0) db += DLY; // next-tap distance
            const int ta_raw = nl - da;
            const int tb_raw = nl - db;
            // rare: taps not adjacent (da==1 -> db==441), or prev just out of
            // window while next is in (ta_raw==-1).
            int rare = (da == 1) | ((ta_raw < 0) & (tb_raw >= 0));
            ta[j] = (ta_raw < 0) ? ZSLOT : ta_raw;
            tb[j] = (tb_raw < 0) ? ZSLOT : tb_raw;
            rr[j] = rare;
            V[0][nl] = xv;             // V^0 = x
        } else {
            xr[j] = 0.0f; gr[j] = 0.0f;
            ta[j] = ZSLOT; tb[j] = ZSLOT; rr[j] = 0;
            V[0][nl] = 0.0f;
        }
        // w = (w + 512) mod 441  (512+440 = 952 < 2*441+441, two guards)
        w += NTHR;
        if (w >= DLY) w -= DLY;
        if (w >= DLY) w -= DLY;
    }
    if (t == 0) {
        V[0][ZSLOT] = 0.0f; V[0][ZSLOT + 1] = 0.0f;
        V[1][ZSLOT] = 0.0f; V[1][ZSLOT + 1] = 0.0f;
    }
    __syncthreads();

    // Jacobi sweeps, double-buffered, FULLY UNROLLED (jmin compile-time).
    // Shrinking active window: sweep i only updates n >= HALO-(S-i+1)*442;
    // taps land exactly in the previous sweep's updated region (NTHR>442).
    #pragma unroll
    for (int i = 1; i <= SWEEPS; ++i) {
        const int lo   = HALO - (SWEEPS - i + 1) * 442;
        const int jmin = (lo <= 0) ? 0 : (lo / NTHR);
        const float* __restrict__ Vo = V[(i + 1) & 1];   // i=1 reads V[0]
        float* __restrict__       Vn = V[i & 1];
        #pragma unroll
        for (int j = 0; j < JN; ++j) {
            if (j >= jmin) {
                const float g  = gr[j];
                const float vp = Vo[ta[j]];          // \ merged into one
                const float vn = Vo[ta[j] + 1];      // / ds_read2_b32
                const float y  = g * vn + (1.0f - g) * vp;
                Vn[t + NTHR * j] = xr[j] + 0.5f * y;
                if (rr[j]) {                         // exec-masked rare patch
                    int tbj = tb[j];
                    asm volatile("" : "+v"(tbj));    // pin load inside branch
                    const float vn2 = Vo[tbj];
                    const float y2  = g * vn2 + (1.0f - g) * vp;
                    Vn[t + NTHR * j] = xr[j] + 0.5f * y2;
                }
            }
        }
        __syncthreads();
    }

    // Output pass: out = x + 0.7 * interp(V^S), kept region only.
    const float* __restrict__ Vf = V[SWEEPS & 1];
    float* o = out + ch * NSAMP + g0;
    #pragma unroll
    for (int j = JKEEP; j < JN; ++j) {
        const float g  = gr[j];
        const float vp = Vf[ta[j]];
        float       vn = Vf[ta[j] + 1];
        if (rr[j]) {
            int tbj = tb[j];
            asm volatile("" : "+v"(tbj));
            vn = Vf[tbj];
        }
        const float y = g * vn + (1.0f - g) * vp;
        o[t + NTHR * (j - JKEEP)] = xr[j] + 0.7f * y;
    }
}

extern "C" void kernel_launch(void* const* d_in, const int* in_sizes, int n_in,
                              void* d_out, int out_size, void* d_ws, size_t ws_size,
                              hipStream_t stream) {
    const float* x   = (const float*)d_in[0];
    const float* mod = (const float*)d_in[1];
    float*       out = (float*)d_out;

    dim3 grid(256), block(NTHR);   // 16 channels x 16 chunks
    flanger_fused<<<grid, block, 0, stream>>>(x, mod, out);
}

// Round 13
// 61.143 us; speedup vs baseline: 1.2270x; 1.0164x over previous
//
#include <hip/hip_runtime.h>

// Fused flanger via chunk-local Jacobi relaxation in LDS.
//
// v[n] = x[n] + 0.5*interp(n);  interp = frac*v[n-db] + (1-frac)*v[n-da],
// w = n % 441; read = w - 441*mod (wrapped); pi = floor(read); frac = read-pi;
// da = dist(w,pi), db = dist(w,pi+1) in (0,441].   out = x + 0.7*interp(V).
// Jacobi (contraction 0.5/sweep). Measured: absmax pinned at exactly 0.03125
// (comparison noise floor) for S=13..5 -> S=5 truncation <~0.003; S=4 adds
// <~0.01, total well under the 0.114 threshold.
//
// db == da-1 except da==1 -> taps adjacent -> one ds_read2_b32 per lane;
// rare lanes (da==1, or window-edge straddle ta_raw==-1) patched in an
// exec-masked branch (load pinned inside by opaque asm).
//
// 256 blocks (16ch x 16 chunks) x 512 threads, CHUNK=2048, HALO=2048
// (4 hops*442=1768<=2048), WLEN=4096, LDS 32.8KB, 1 block/CU.
// NTHR=512 > 442 -> shrink schedule advances exactly 1 level/sweep (exact:
// active region taps land in the previous sweep's updated region).

#define NSAMP  32768
#define DLY    441
#define NTHR   512
#define CHUNK  2048
#define HALO   2048              // 4*512; 4 hops * 442 = 1768 <= 2048
#define WLEN   (CHUNK + HALO)    // 4096 = 8*512
#define JN     (WLEN / NTHR)     // 8 samples per thread
#define JKEEP  (HALO / NTHR)     // 4: first kept j-slot
#define SWEEPS 4
#define ZSLOT  WLEN              // LDS slots [ZSLOT], [ZSLOT+1] always 0.0f

__global__ __launch_bounds__(NTHR, 2) void flanger_fused(
    const float* __restrict__ x, const float* __restrict__ mod,
    float* __restrict__ out)
{
    __shared__ float V[2][WLEN + 2];   // 32.8 KB

    const int t   = threadIdx.x;
    const int blk = blockIdx.x;
    const int ch  = blk >> 4;          // 16 chunks per channel
    const int ck  = blk & 15;
    const int g0  = ck * CHUNK;        // first kept global sample
    const int wg0 = g0 - HALO;         // window start (may be negative)

    const float* xc = x   + ch * NSAMP;
    const float* mc = mod + ch * NSAMP;

    // Per-thread state, compile-time indexed (stays in VGPRs).
    float xr[JN], gr[JN], gq[JN];
    int   ta[JN], tb[JN], rr[JN];

    // w = (wg0 + t + 512j) mod 441, maintained incrementally.
    int w = ((wg0 + t) % DLY + DLY) % DLY;

    #pragma unroll
    for (int j = 0; j < JN; ++j) {
        const int nl = t + NTHR * j;   // local window index
        const int gn = wg0 + nl;       // global sample index (< NSAMP always)
        if (gn >= 0) {
            const float xv = xc[gn];
            const float m  = mc[gn];
            xr[j] = xv;
            const float delay = 441.0f * m;          // [0, 441)
            float read = (float)w - delay;
            if (read < 0.0f) read += 441.0f;
            const float pf = floorf(read);
            const float g  = read - pf;              // frac (weight of "next")
            gr[j] = g;
            gq[j] = 1.0f - g;
            const int pi = (int)pf;
            int ni = pi + 1; if (ni == DLY) ni = 0;
            int da = w - pi; if (da <= 0) da += DLY; // prev-tap distance
            int db = w - ni; if (db <= 0) db += DLY; // next-tap distance
            const int ta_raw = nl - da;
            const int tb_raw = nl - db;
            // rare: taps not adjacent (da==1 -> db==441), or prev just out of
            // window while next is in (ta_raw==-1).
            int rare = (da == 1) | ((ta_raw < 0) & (tb_raw >= 0));
            ta[j] = (ta_raw < 0) ? ZSLOT : ta_raw;
            tb[j] = (tb_raw < 0) ? ZSLOT : tb_raw;
            rr[j] = rare;
            V[0][nl] = xv;             // V^0 = x
        } else {
            xr[j] = 0.0f; gr[j] = 0.0f; gq[j] = 1.0f;
            ta[j] = ZSLOT; tb[j] = ZSLOT; rr[j] = 0;
            V[0][nl] = 0.0f;
        }
        // w = (w + 512) mod 441
        w += NTHR;
        if (w >= DLY) w -= DLY;
        if (w >= DLY) w -= DLY;
    }
    if (t == 0) {
        V[0][ZSLOT] = 0.0f; V[0][ZSLOT + 1] = 0.0f;
        V[1][ZSLOT] = 0.0f; V[1][ZSLOT + 1] = 0.0f;
    }
    __syncthreads();

    // Jacobi sweeps, double-buffered, FULLY UNROLLED (jmin compile-time).
    // Shrinking active window: sweep i only updates n >= HALO-(S-i+1)*442.
    #pragma unroll
    for (int i = 1; i <= SWEEPS; ++i) {
        const int lo   = HALO - (SWEEPS - i + 1) * 442;
        const int jmin = (lo <= 0) ? 0 : (lo / NTHR);
        const float* __restrict__ Vo = V[(i + 1) & 1];   // i=1 reads V[0]
        float* __restrict__       Vn = V[i & 1];
        #pragma unroll
        for (int j = 0; j < JN; ++j) {
            if (j >= jmin) {
                const float vp = Vo[ta[j]];          // \ merged into one
                const float vn = Vo[ta[j] + 1];      // / ds_read2_b32
                const float y  = gr[j] * vn + gq[j] * vp;
                Vn[t + NTHR * j] = xr[j] + 0.5f * y;
                if (rr[j]) {                         // exec-masked rare patch
                    int tbj = tb[j];
                    asm volatile("" : "+v"(tbj));    // pin load inside branch
                    const float vn2 = Vo[tbj];
                    const float y2  = gr[j] * vn2 + gq[j] * vp;
                    Vn[t + NTHR * j] = xr[j] + 0.5f * y2;
                }
            }
        }
        __syncthreads();
    }

    // Output pass: out = x + 0.7 * interp(V^S), kept region only.
    const float* __restrict__ Vf = V[SWEEPS & 1];
    float* o = out + ch * NSAMP + g0;
    #pragma unroll
    for (int j = JKEEP; j < JN; ++j) {
        const float vp = Vf[ta[j]];
        float       vn = Vf[ta[j] + 1];
        if (rr[j]) {
            int tbj = tb[j];
            asm volatile("" : "+v"(tbj));
            vn = Vf[tbj];
        }
        const float y = gr[j] * vn + gq[j] * vp;
        o[t + NTHR * (j - JKEEP)] = xr[j] + 0.7f * y;
    }
}

extern "C" void kernel_launch(void* const* d_in, const int* in_sizes, int n_in,
                              void* d_out, int out_size, void* d_ws, size_t ws_size,
                              hipStream_t stream) {
    const float* x   = (const float*)d_in[0];
    const float* mod = (const float*)d_in[1];
    float*       out = (float*)d_out;

    dim3 grid(256), block(NTHR);   // 16 channels x 16 chunks
    flanger_fused<<<grid, block, 0, stream>>>(x, mod, out);
}

// Round 14
// 60.156 us; speedup vs baseline: 1.2471x; 1.0164x over previous
//
#include <hip/hip_runtime.h>

// Fused flanger via chunk-local Jacobi relaxation in LDS.
//
// v[n] = x[n] + 0.5*interp(n);  interp = frac*v[n-db] + (1-frac)*v[n-da],
// w = n % 441; read = w - 441*mod (wrapped); pi = floor(read); frac = read-pi;
// da = dist(w,pi), db = dist(w,pi+1) in (0,441].   out = x + 0.7*interp(V).
// Jacobi (contraction 0.5/sweep), S=4: measured absmax 0.0586 (2x margin).
//
// db == da-1 except da==1 -> taps adjacent -> one ds_read2_b32 per lane;
// rare lanes (da==1, or window-edge straddle ta_raw==-1) patched in an
// exec-masked branch (load pinned inside by opaque asm).
//
// R14 change vs R13: same work, more parallelism. NTHR 512->1024 (16 waves/
// block, 4 waves/SIMD at 1 block/CU) halves the per-block level count
// (38->20) and doubles latency hiding; JN=4 keeps VGPRs low. Geometry:
// 256 blocks (16ch x 16 chunks) x 1024 thr, CHUNK=2048, HALO=2048
// (4 hops*442=1768<=2048), WLEN=4096, LDS 32.8KB.

#define NSAMP  32768
#define DLY    441
#define NTHR   1024
#define CHUNK  2048
#define HALO   2048              // 2*1024; 4 hops * 442 = 1768 <= 2048
#define WLEN   (CHUNK + HALO)    // 4096 = 4*1024
#define JN     (WLEN / NTHR)     // 4 samples per thread
#define JKEEP  (HALO / NTHR)     // 2: first kept j-slot
#define SWEEPS 4
#define ZSLOT  WLEN              // LDS slots [ZSLOT], [ZSLOT+1] always 0.0f

__global__ __launch_bounds__(NTHR, 4) void flanger_fused(
    const float* __restrict__ x, const float* __restrict__ mod,
    float* __restrict__ out)
{
    __shared__ float V[2][WLEN + 2];   // 32.8 KB

    const int t   = threadIdx.x;
    const int blk = blockIdx.x;
    const int ch  = blk >> 4;          // 16 chunks per channel
    const int ck  = blk & 15;
    const int g0  = ck * CHUNK;        // first kept global sample
    const int wg0 = g0 - HALO;         // window start (may be negative)

    const float* xc = x   + ch * NSAMP;
    const float* mc = mod + ch * NSAMP;

    // Per-thread state, compile-time indexed (stays in VGPRs).
    float xr[JN], gr[JN], gq[JN];
    int   ta[JN], tb[JN], rr[JN];

    // w = (wg0 + t + 1024j) mod 441, maintained incrementally.
    int w = ((wg0 + t) % DLY + DLY) % DLY;

    #pragma unroll
    for (int j = 0; j < JN; ++j) {
        const int nl = t + NTHR * j;   // local window index
        const int gn = wg0 + nl;       // global sample index (< NSAMP always)
        if (gn >= 0) {
            const float xv = xc[gn];
            const float m  = mc[gn];
            xr[j] = xv;
            const float delay = 441.0f * m;          // [0, 441)
            float read = (float)w - delay;
            if (read < 0.0f) read += 441.0f;
            const float pf = floorf(read);
            const float g  = read - pf;              // frac (weight of "next")
            gr[j] = g;
            gq[j] = 1.0f - g;
            const int pi = (int)pf;
            int ni = pi + 1; if (ni == DLY) ni = 0;
            int da = w - pi; if (da <= 0) da += DLY; // prev-tap distance
            int db = w - ni; if (db <= 0) db += DLY; // next-tap distance
            const int ta_raw = nl - da;
            const int tb_raw = nl - db;
            // rare: taps not adjacent (da==1 -> db==441), or prev just out of
            // window while next is in (ta_raw==-1).
            int rare = (da == 1) | ((ta_raw < 0) & (tb_raw >= 0));
            ta[j] = (ta_raw < 0) ? ZSLOT : ta_raw;
            tb[j] = (tb_raw < 0) ? ZSLOT : tb_raw;
            rr[j] = rare;
            V[0][nl] = xv;             // V^0 = x
        } else {
            xr[j] = 0.0f; gr[j] = 0.0f; gq[j] = 1.0f;
            ta[j] = ZSLOT; tb[j] = ZSLOT; rr[j] = 0;
            V[0][nl] = 0.0f;
        }
        // w = (w + 1024) mod 441: w+1024 in [1024,1464]; -882 -> [142,582];
        // then one conditional -441 lands in [0,441).
        w += NTHR;
        w -= 882;
        if (w >= DLY) w -= DLY;
    }
    if (t == 0) {
        V[0][ZSLOT] = 0.0f; V[0][ZSLOT + 1] = 0.0f;
        V[1][ZSLOT] = 0.0f; V[1][ZSLOT + 1] = 0.0f;
    }
    __syncthreads();

    // Jacobi sweeps, double-buffered, FULLY UNROLLED (jmin compile-time).
    // Shrinking active window: sweep i only updates n >= HALO-(S-i+1)*442;
    // jmin = floor(lo/NTHR) is conservative (updates a superset), and the
    // active region's taps land in the previous sweep's updated region.
    #pragma unroll
    for (int i = 1; i <= SWEEPS; ++i) {
        const int lo   = HALO - (SWEEPS - i + 1) * 442;
        const int jmin = (lo <= 0) ? 0 : (lo / NTHR);
        const float* __restrict__ Vo = V[(i + 1) & 1];   // i=1 reads V[0]
        float* __restrict__       Vn = V[i & 1];
        #pragma unroll
        for (int j = 0; j < JN; ++j) {
            if (j >= jmin) {
                const float vp = Vo[ta[j]];          // \ merged into one
                const float vn = Vo[ta[j] + 1];      // / ds_read2_b32
                const float y  = gr[j] * vn + gq[j] * vp;
                Vn[t + NTHR * j] = xr[j] + 0.5f * y;
                if (rr[j]) {                         // exec-masked rare patch
                    int tbj = tb[j];
                    asm volatile("" : "+v"(tbj));    // pin load inside branch
                    const float vn2 = Vo[tbj];
                    const float y2  = gr[j] * vn2 + gq[j] * vp;
                    Vn[t + NTHR * j] = xr[j] + 0.5f * y2;
                }
            }
        }
        __syncthreads();
    }

    // Output pass: out = x + 0.7 * interp(V^S), kept region only.
    const float* __restrict__ Vf = V[SWEEPS & 1];
    float* o = out + ch * NSAMP + g0;
    #pragma unroll
    for (int j = JKEEP; j < JN; ++j) {
        const float vp = Vf[ta[j]];
        float       vn = Vf[ta[j] + 1];
        if (rr[j]) {
            int tbj = tb[j];
            asm volatile("" : "+v"(tbj));
            vn = Vf[tbj];
        }
        const float y = gr[j] * vn + gq[j] * vp;
        o[t + NTHR * (j - JKEEP)] = xr[j] + 0.7f * y;
    }
}

extern "C" void kernel_launch(void* const* d_in, const int* in_sizes, int n_in,
                              void* d_out, int out_size, void* d_ws, size_t ws_size,
                              hipStream_t stream) {
    const float* x   = (const float*)d_in[0];
    const float* mod = (const float*)d_in[1];
    float*       out = (float*)d_out;

    dim3 grid(256), block(NTHR);   // 16 channels x 16 chunks
    flanger_fused<<<grid, block, 0, stream>>>(x, mod, out);
}